// Round 7
// baseline (9366.925 us; speedup 1.0000x reference)
//
#include <hip/hip_runtime.h>
#include <cstdint>
#include <cstddef>

typedef unsigned short u16;
typedef __bf16 bf16_t;
typedef bf16_t bf16x8 __attribute__((ext_vector_type(8)));
typedef float f32x4 __attribute__((ext_vector_type(4)));

static constexpr int HID    = 512;
static constexpr int BATCH  = 1024;
static constexpr int NSTEPS = 95;   // T + future - 1 = 64 + 31
static constexpr int T_OBS  = 64;
static constexpr int OUTW   = 190;  // 2 * NSTEPS

// ---------- helpers ----------
__device__ __forceinline__ u16 f2bf(float x) {
  union { float f; uint32_t u; } c; c.f = x;
  uint32_t r = c.u + 0x7fffu + ((c.u >> 16) & 1u);   // RNE
  return (u16)(r >> 16);
}
__device__ __forceinline__ float bf2f(u16 h) {
  union { uint32_t u; float f; } c; c.u = ((uint32_t)h) << 16;
  return c.f;
}
__device__ __forceinline__ float sigm(float x) { return 1.f / (1.f + __expf(-x)); }
__device__ __forceinline__ float tanh_fast(float x) {
  float ax = fabsf(x);
  float t  = __expf(-2.f * ax);
  float r  = (1.f - t) / (1.f + t);
  return x < 0.f ? -r : r;
}

// ---------- weight prep (gate-interleaved column order) ----------
// col n = 4*h + g  <->  original row r = g*512 + h
__global__ void prep_bt1(const float* __restrict__ Whh1, u16* __restrict__ Bt1) {
  int idx = blockIdx.x * 256 + threadIdx.x;       // 2048*1024
  int n = idx >> 10, kk = idx & 1023;
  int r = (n & 3) * HID + (n >> 2);
  int k = kk & 511;
  float v = Whh1[r * HID + k];
  u16 hi = f2bf(v);
  Bt1[idx] = (kk < 512) ? hi : f2bf(v - bf2f(hi));
}
__global__ void prep_bt2(const float* __restrict__ Wih2, const float* __restrict__ Whh2,
                         u16* __restrict__ Bt2) {
  int idx = blockIdx.x * 256 + threadIdx.x;       // 2048*2048
  int n = idx >> 11, kk = idx & 2047;
  int r = (n & 3) * HID + (n >> 2);
  int k = kk & 1023;
  float v = (k < 512) ? Wih2[r * HID + k] : Whh2[r * HID + (k - 512)];
  u16 hi = f2bf(v);
  Bt2[idx] = (kk < 1024) ? hi : f2bf(v - bf2f(hi));
}
__global__ void prep_small(const float* __restrict__ b1, const float* __restrict__ b2,
                           const float* __restrict__ Wih1,
                           float* __restrict__ b1p, float* __restrict__ b2p,
                           float* __restrict__ w1p) {
  int n = blockIdx.x * 256 + threadIdx.x;
  if (n >= 2048) return;
  int r = (n & 3) * HID + (n >> 2);
  b1p[n] = b1[r];
  b2p[n] = b2[r];
  w1p[2 * n + 0] = Wih1[2 * r + 0];
  w1p[2 * n + 1] = Wih1[2 * r + 1];
}
__global__ void init_out(const float* __restrict__ bl, float* __restrict__ out) {
  int i = blockIdx.x * 256 + threadIdx.x;
  if (i < BATCH * OUTW) out[i] = bl[i & 1];
}

// ---------- fused gate-GEMM + LSTM cell (+ optional out-projection) ----------
struct GArgs {
  const u16* Ah0; const u16* Ah1;   // hi activation chunks ([1024][512] each)
  const u16* Al0; const u16* Al1;   // lo activation chunks
  const u16* Bt;                    // bf16 weight panel [2048][2*KTOT] (hi|lo)
  const float* bias;                // reordered bias [2048]
  const float* xptr; int xstride;   // layer-1 input (2 floats/row)
  const float* wih;                 // reordered Wih1 [2048][2]
  float* CstT;                      // cell state TRANSPOSED [512][1024], RMW
  u16* Hh; u16* Hl;                 // output h hi/lo [1024][512]
  const float* wl;                  // Wl [2][512] original order
  float* oacc;                      // out + 2t (atomic accumulate)
};

#define MFMA_(A, B, C) C = __builtin_amdgcn_mfma_f32_16x16x32_bf16(A, B, C, 0, 0, 0)

#define EPI(I, J, ACC)                                                          \
  {                                                                             \
    const int hl_ = wq * 8 + (I) * 4 + lq;                                      \
    const int hg_ = hg0 + hl_;                                                  \
    const int ml_ = wp * 32 + (J) * 16 + l15;                                   \
    const int mg_ = mg0 + ml_;                                                  \
    const float4 b4_ = *(const float4*)(bias + 4 * hg_);                        \
    float g0_ = ACC[0] + b4_.x, g1_ = ACC[1] + b4_.y;                           \
    float g2_ = ACC[2] + b4_.z, g3_ = ACC[3] + b4_.w;                           \
    if (HASX) {                                                                 \
      const float x0_ = xptr[(size_t)mg_ * xstride + 0];                        \
      const float x1_ = xptr[(size_t)mg_ * xstride + 1];                        \
      const float4 wA_ = *(const float4*)(wih + 8 * hg_);                       \
      const float4 wB_ = *(const float4*)(wih + 8 * hg_ + 4);                   \
      g0_ += x0_ * wA_.x + x1_ * wA_.y;  g1_ += x0_ * wA_.z + x1_ * wA_.w;      \
      g2_ += x0_ * wB_.x + x1_ * wB_.y;  g3_ += x0_ * wB_.z + x1_ * wB_.w;      \
    }                                                                           \
    const float ig_ = sigm(g0_), fg_ = sigm(g1_);                               \
    const float gg_ = tanh_fast(g2_), og_ = sigm(g3_);                          \
    float* cp_ = CstT + (size_t)hg_ * BATCH + mg_;                              \
    const float cn_ = fg_ * (*cp_) + ig_ * gg_;                                 \
    *cp_ = cn_;                                                                 \
    const float hn_ = og_ * tanh_fast(cn_);                                     \
    const u16 hi_ = f2bf(hn_);                                                  \
    Hsh[ml_ * 17 + hl_] = hi_;                                                  \
    Hsl[ml_ * 17 + hl_] = f2bf(hn_ - bf2f(hi_));                                \
    if (PROJ) {                                                                 \
      if ((J) == 0) { s0a += hn_ * wl[hg_]; s1a += hn_ * wl[HID + hg_]; }       \
      else          { s0b += hn_ * wl[hg_]; s1b += hn_ * wl[HID + hg_]; }       \
    }                                                                           \
  }

// BM=BN=64, NO LDS STAGING, NO K-loop barriers. Each wave reads its MFMA
// fragments directly from global (L1/L2-cached); 16-row scatter costs the same
// VMEM segment count as a coalesced load (1KB/inst either way), and each row
// read covers a full 128B line per K-step. Swapped MFMA (W x H) -> in-register
// epilogue. 3-pass bf16 hi/lo split fused in one K-walk (hh + lh + hl).
template <int KTOT, bool HASX, bool PROJ>
__device__ __forceinline__ void run_gemm(const GArgs& g, int mt, int nt, char* smem) {
  const u16* const Ah0 = g.Ah0;  const u16* const Ah1 = g.Ah1;
  const u16* const Al0 = g.Al0;  const u16* const Al1 = g.Al1;
  const u16* const Bt  = g.Bt;
  const float* const bias = g.bias;
  const float* const xptr = g.xptr; const int xstride = g.xstride;
  const float* const wih  = g.wih;
  float* const CstT = g.CstT;
  u16* const Hh = g.Hh;  u16* const Hl = g.Hl;
  const float* const wl = g.wl;
  float* const oacc = g.oacc;

  const int tid = threadIdx.x;
  const int wid = tid >> 6, lane = tid & 63;
  const int wq = wid >> 1, wp = wid & 1;   // wq: N(gate)-half, wp: M(batch)-half
  const int l15 = lane & 15, lq = lane >> 4;

  const int hrow0 = mt * 64 + wp * 32 + l15;           // H rows (m)
  const int hrow1 = hrow0 + 16;
  const int wrow0 = nt * 64 + wq * 32 + l15;           // W rows (n)
  const int wrow1 = wrow0 + 16;

  // per-lane base pointers (k-offset lq*8 folded in)
  const u16* const a0h = Ah0 + (size_t)hrow0 * HID + lq * 8;
  const u16* const a1h = Ah0 + (size_t)hrow1 * HID + lq * 8;
  const u16* const a0l = Al0 + (size_t)hrow0 * HID + lq * 8;
  const u16* const a1l = Al0 + (size_t)hrow1 * HID + lq * 8;
  const u16* const b0p = Bt + (size_t)wrow0 * (2 * KTOT) + lq * 8;
  const u16* const b1p = Bt + (size_t)wrow1 * (2 * KTOT) + lq * 8;
  // second A chunk (layer 2 only)
  const u16* const a0h2 = (KTOT == 1024) ? (Ah1 + (size_t)hrow0 * HID + lq * 8) : a0h;
  const u16* const a1h2 = (KTOT == 1024) ? (Ah1 + (size_t)hrow1 * HID + lq * 8) : a1h;
  const u16* const a0l2 = (KTOT == 1024) ? (Al1 + (size_t)hrow0 * HID + lq * 8) : a0l;
  const u16* const a1l2 = (KTOT == 1024) ? (Al1 + (size_t)hrow1 * HID + lq * 8) : a1l;

  f32x4 acc00 = {}, acc01 = {}, acc10 = {}, acc11 = {};
  constexpr int NS = KTOT / 32;            // 32-wide k slices

#pragma unroll 2
  for (int s = 0; s < NS; ++s) {
    const int kb = s * 32;                 // global k (weight panel column)
    const int ka = (KTOT == 1024) ? (kb & 511) : kb;  // k within 512-wide A panel
    const bool c2 = (KTOT == 1024) && (kb >= 512);
    const u16* A0h = c2 ? a0h2 : a0h;
    const u16* A1h = c2 ? a1h2 : a1h;
    const u16* A0l = c2 ? a0l2 : a0l;
    const u16* A1l = c2 ? a1l2 : a1l;
    const bf16x8 ah0 = *(const bf16x8*)(A0h + ka);
    const bf16x8 ah1 = *(const bf16x8*)(A1h + ka);
    const bf16x8 al0 = *(const bf16x8*)(A0l + ka);
    const bf16x8 al1 = *(const bf16x8*)(A1l + ka);
    const bf16x8 bh0 = *(const bf16x8*)(b0p + kb);
    const bf16x8 bh1 = *(const bf16x8*)(b1p + kb);
    const bf16x8 bl0 = *(const bf16x8*)(b0p + KTOT + kb);
    const bf16x8 bl1 = *(const bf16x8*)(b1p + KTOT + kb);
    MFMA_(bh0, ah0, acc00); MFMA_(bh0, ah1, acc01);    // hi(W) * hi(H)
    MFMA_(bh1, ah0, acc10); MFMA_(bh1, ah1, acc11);
    MFMA_(bl0, ah0, acc00); MFMA_(bl0, ah1, acc01);    // lo(W) * hi(H)
    MFMA_(bl1, ah0, acc10); MFMA_(bl1, ah1, acc11);
    MFMA_(bh0, al0, acc00); MFMA_(bh0, al1, acc01);    // hi(W) * lo(H)
    MFMA_(bh1, al0, acc10); MFMA_(bh1, al1, acc11);
  }

  // ---- in-register epilogue ----
  u16* const Hsh = (u16*)smem;               // [64][17]
  u16* const Hsl = Hsh + 64 * 17;

  const int mg0 = mt * 64, hg0 = nt * 16;
  float s0a = 0.f, s1a = 0.f, s0b = 0.f, s1b = 0.f;

  EPI(0, 0, acc00); EPI(0, 1, acc01);
  EPI(1, 0, acc10); EPI(1, 1, acc11);

  if (PROJ) {                                // reduce over lq (wave's 8 h vals)
    s0a += __shfl_xor(s0a, 16); s0a += __shfl_xor(s0a, 32);
    s1a += __shfl_xor(s1a, 16); s1a += __shfl_xor(s1a, 32);
    s0b += __shfl_xor(s0b, 16); s0b += __shfl_xor(s0b, 32);
    s1b += __shfl_xor(s1b, 16); s1b += __shfl_xor(s1b, 32);
    if (lq == 0) {
      int mgA = mg0 + wp * 32 + l15;
      unsafeAtomicAdd(&oacc[(size_t)mgA * OUTW + 0], s0a);
      unsafeAtomicAdd(&oacc[(size_t)mgA * OUTW + 1], s1a);
      int mgB = mgA + 16;
      unsafeAtomicAdd(&oacc[(size_t)mgB * OUTW + 0], s0b);
      unsafeAtomicAdd(&oacc[(size_t)mgB * OUTW + 1], s1b);
    }
  }

  __syncthreads();                           // H stage complete
#pragma unroll
  for (int q = 0; q < 4; ++q) {              // coalesced H writeback
    int m = (tid >> 4) + 16 * q, c = tid & 15;
    Hh[(size_t)(mg0 + m) * HID + hg0 + c] = Hsh[m * 17 + c];
    Hl[(size_t)(mg0 + m) * HID + hg0 + c] = Hsl[m * 17 + c];
  }
}

// XCD-pinned tile mapping: xcd = bid&7 always owns nt in [xcd*4, xcd*4+4)
template <int KTOT, bool HASX, bool PROJ>
__global__ __launch_bounds__(256, 4) void step_single(GArgs ga) {
  __shared__ __align__(16) char smem[4352];
  int bid = blockIdx.x;
  int xc = bid & 7, j = bid >> 3;            // j in [0,64)
  int nt = xc * 4 + (j & 3);
  int mt = j >> 2;                           // 0..15
  run_gemm<KTOT, HASX, PROJ>(ga, mt, nt, smem);
}

// grid 1024: bid<512 -> L2(t) (+proj), else -> L1(t+1)  (independent GEMMs)
__global__ __launch_bounds__(256, 4) void step_fused(GArgs g2, GArgs g1) {
  __shared__ __align__(16) char smem[4352];
  int bid = blockIdx.x;
  int b = bid & 511;
  int xc = b & 7, j = b >> 3;                // j in [0,64)
  int nt = xc * 4 + (j & 3);
  int mt = j >> 2;
  if (bid < 512) run_gemm<1024, false, true>(g2, mt, nt, smem);
  else           run_gemm<512, true, false>(g1, mt, nt, smem);
}

// ---------- host ----------
extern "C" void kernel_launch(void* const* d_in, const int* in_sizes, int n_in,
                              void* d_out, int out_size, void* d_ws, size_t ws_size,
                              hipStream_t stream) {
  const float* x    = (const float*)d_in[0];
  const float* Wih1 = (const float*)d_in[1];
  const float* Whh1 = (const float*)d_in[2];
  const float* b1   = (const float*)d_in[3];
  const float* Wih2 = (const float*)d_in[4];
  const float* Whh2 = (const float*)d_in[5];
  const float* b2   = (const float*)d_in[6];
  const float* Wl   = (const float*)d_in[7];
  const float* bl   = (const float*)d_in[8];
  float* out = (float*)d_out;
  (void)in_sizes; (void)n_in; (void)out_size; (void)ws_size;

  char* p = (char*)d_ws;
  auto alloc = [&](size_t bytes) -> char* {
    char* r = p; p += (bytes + 255) & ~(size_t)255; return r;
  };
  u16* Bt1 = (u16*)alloc((size_t)2048 * 1024 * 2);   // 4 MB
  u16* Bt2 = (u16*)alloc((size_t)2048 * 2048 * 2);   // 8 MB
  char* state0 = p;
  u16* Hb[8];                                        // H1h[2],H1l[2],H2h[2],H2l[2]
  for (int i = 0; i < 8; ++i) Hb[i] = (u16*)alloc((size_t)BATCH * HID * 2);
  float* C1 = (float*)alloc((size_t)BATCH * HID * 4);  // stored [512][1024]
  float* C2 = (float*)alloc((size_t)BATCH * HID * 4);
  size_t state_bytes = (size_t)(p - state0);
  float* b1p = (float*)alloc(2048 * 4);
  float* b2p = (float*)alloc(2048 * 4);
  float* w1p = (float*)alloc(2048 * 2 * 4);

  hipMemsetAsync(state0, 0, state_bytes, stream);    // h,c = 0
  init_out<<<(BATCH * OUTW + 255) / 256, 256, 0, stream>>>(bl, out);
  prep_bt1<<<8192, 256, 0, stream>>>(Whh1, Bt1);
  prep_bt2<<<16384, 256, 0, stream>>>(Wih2, Whh2, Bt2);
  prep_small<<<8, 256, 0, stream>>>(b1, b2, Wih1, b1p, b2p, w1p);

  auto mkL1 = [&](int t) -> GArgs {
    int par = t & 1, prev = par ^ 1;
    GArgs a{};
    a.Ah0 = Hb[0 + prev]; a.Ah1 = nullptr;
    a.Al0 = Hb[2 + prev]; a.Al1 = nullptr;
    a.Bt = Bt1; a.bias = b1p;
    a.xptr = (t < T_OBS) ? (x + 2 * t) : (out + 2 * (t - 1));
    a.xstride = (t < T_OBS) ? (2 * T_OBS) : OUTW;
    a.wih = w1p; a.CstT = C1;
    a.Hh = Hb[0 + par]; a.Hl = Hb[2 + par];
    a.wl = nullptr; a.oacc = nullptr;
    return a;
  };
  auto mkL2 = [&](int t) -> GArgs {
    int par = t & 1, prev = par ^ 1;
    GArgs a{};
    a.Ah0 = Hb[0 + par];  a.Ah1 = Hb[4 + prev];   // k<512: H1(t), k>=512: H2(t-1)
    a.Al0 = Hb[2 + par];  a.Al1 = Hb[6 + prev];
    a.Bt = Bt2; a.bias = b2p;
    a.xptr = nullptr; a.xstride = 0; a.wih = nullptr;
    a.CstT = C2;
    a.Hh = Hb[4 + par]; a.Hl = Hb[6 + par];
    a.wl = Wl; a.oacc = out + 2 * t;
    return a;
  };

  // step 0 layer 1
  step_single<512, true, false><<<512, 256, 0, stream>>>(mkL1(0));
  // observed steps: L2(t) and L1(t+1) are independent -> one 1024-WG dispatch
  for (int t = 0; t < T_OBS - 1; ++t)
    step_fused<<<1024, 256, 0, stream>>>(mkL2(t), mkL1(t + 1));
  // last observed L2 (writes out[63])
  step_single<1024, false, true><<<512, 256, 0, stream>>>(mkL2(T_OBS - 1));
  // future steps: strict chain L1 -> L2(+proj) -> L1 ...
  for (int t = T_OBS; t < NSTEPS; ++t) {
    step_single<512, true, false><<<512, 256, 0, stream>>>(mkL1(t));
    step_single<1024, false, true><<<512, 256, 0, stream>>>(mkL2(t));
  }
}

// Round 8
// 3830.067 us; speedup vs baseline: 2.4456x; 2.4456x over previous
//
#include <hip/hip_runtime.h>
#include <cstdint>
#include <cstddef>

typedef unsigned short u16;
typedef __bf16 bf16_t;
typedef bf16_t bf16x8 __attribute__((ext_vector_type(8)));
typedef float f32x4 __attribute__((ext_vector_type(4)));

static constexpr int HID    = 512;
static constexpr int BATCH  = 1024;
static constexpr int NSTEPS = 95;   // T + future - 1 = 64 + 31
static constexpr int T_OBS  = 64;
static constexpr int OUTW   = 190;  // 2 * NSTEPS

// ---------- helpers ----------
__device__ __forceinline__ u16 f2bf(float x) {
  union { float f; uint32_t u; } c; c.f = x;
  uint32_t r = c.u + 0x7fffu + ((c.u >> 16) & 1u);   // RNE
  return (u16)(r >> 16);
}
__device__ __forceinline__ float bf2f(u16 h) {
  union { uint32_t u; float f; } c; c.u = ((uint32_t)h) << 16;
  return c.f;
}
__device__ __forceinline__ float sigm(float x) { return 1.f / (1.f + __expf(-x)); }
__device__ __forceinline__ float tanh_fast(float x) {
  float ax = fabsf(x);
  float t  = __expf(-2.f * ax);
  float r  = (1.f - t) / (1.f + t);
  return x < 0.f ? -r : r;
}

// global_load_lds width-16: wave-uniform LDS base, per-lane global src.
typedef __attribute__((address_space(1))) const uint32_t glb_u32;
typedef __attribute__((address_space(3))) uint32_t lds_u32;
__device__ __forceinline__ void glds16(const void* g, void* l) {
  __builtin_amdgcn_global_load_lds((glb_u32*)g, (lds_u32*)l, 16, 0, 0);
}

// ---------- weight prep ----------
// Swizzled-interleaved panel layout (matches the LDS image gload_lds produces):
// row n = gate-interleaved col (n=4h+g <-> r=g*512+h), row length 2*KT u16,
// organized as blks of 128 u16 (256B): [16 slots of 8 u16]; slot s holds
// logical chunk c = s ^ (n&15); chunks 0..7 = hi[k=blk*64+8c'..], 8..15 = lo.
__global__ void prep_btx1(const float* __restrict__ Whh1, u16* __restrict__ Bt) {
  int idx = blockIdx.x * 256 + threadIdx.x;       // 2048 * 1024
  int n = idx >> 10, t = idx & 1023;
  int blk = t >> 7, slot = (t >> 3) & 15, e = t & 7;
  int ch = slot ^ (n & 15);
  int k = blk * 64 + (ch & 7) * 8 + e;
  int r = (n & 3) * HID + (n >> 2);
  float v = Whh1[r * HID + k];
  u16 hi = f2bf(v);
  Bt[idx] = (ch < 8) ? hi : f2bf(v - bf2f(hi));
}
__global__ void prep_btx2(const float* __restrict__ Wih2, const float* __restrict__ Whh2,
                          u16* __restrict__ Bt) {
  int idx = blockIdx.x * 256 + threadIdx.x;       // 2048 * 2048
  int n = idx >> 11, t = idx & 2047;
  int blk = t >> 7, slot = (t >> 3) & 15, e = t & 7;
  int ch = slot ^ (n & 15);
  int k = blk * 64 + (ch & 7) * 8 + e;            // 0..1023
  int r = (n & 3) * HID + (n >> 2);
  float v = (k < 512) ? Wih2[r * HID + k] : Whh2[r * HID + (k - 512)];
  u16 hi = f2bf(v);
  Bt[idx] = (ch < 8) ? hi : f2bf(v - bf2f(hi));
}
__global__ void prep_small(const float* __restrict__ b1, const float* __restrict__ b2,
                           const float* __restrict__ Wih1,
                           float* __restrict__ b1p, float* __restrict__ b2p,
                           float* __restrict__ w1p) {
  int n = blockIdx.x * 256 + threadIdx.x;
  if (n >= 2048) return;
  int r = (n & 3) * HID + (n >> 2);
  b1p[n] = b1[r];
  b2p[n] = b2[r];
  w1p[2 * n + 0] = Wih1[2 * r 	+ 0];
  w1p[2 * n + 1] = Wih1[2 * r + 1];
}
__global__ void init_out(const float* __restrict__ bl, float* __restrict__ out) {
  int i = blockIdx.x * 256 + threadIdx.x;
  if (i < BATCH * OUTW) out[i] = bl[i & 1];
}

// ---------- fused gate-GEMM + LSTM cell (+ optional out-projection) ----------
// H state panels (Hx) use the SAME swizzled-interleaved layout as weights:
// [1024 rows][1024 u16] = 8 blks x (16 slots x 8 u16), slot s = chunk s^(row&15),
// chunks 0..7 hi, 8..15 lo. Written swizzled by the epilogue, consumed linearly
// by global_load_lds.
struct GArgs {
  const u16* Ax0; const u16* Ax1;   // A panels (Hx layout); Ax1 = k>=512 (L2)
  const u16* Bt;                    // swizzled weight panel [2048][2*KTOT]
  const float* bias;                // reordered bias [2048]
  const float* xptr; int xstride;   // layer-1 input (2 floats/row)
  const float* wih;                 // reordered Wih1 [2048][2]
  float* CstT;                      // cell state TRANSPOSED [512][1024], RMW
  u16* Hx;                          // output H panel (Hx layout)
  const float* wl;                  // Wl [2][512] original order
  float* oacc;                      // out + 2t (atomic accumulate)
};

// One 32-wide k-slice: 12 frag reads -> 24 MFMAs (pass-fused hh + lh + hl).
#define MFMA_(A, B, C) C = __builtin_amdgcn_mfma_f32_16x16x32_bf16(A, B, C, 0, 0, 0)
#define KKBODY(KKC)                                                             \
  {                                                                             \
    const int so_ = sl0 ^ ((KKC) ? 64 : 0);                                     \
    const bf16x8 ah0_ = *(const bf16x8*)(Asb + arow +     0 + so_);             \
    const bf16x8 ah1_ = *(const bf16x8*)(Asb + arow +  4096 + so_);             \
    const bf16x8 ah2_ = *(const bf16x8*)(Asb + arow +  8192 + so_);             \
    const bf16x8 ah3_ = *(const bf16x8*)(Asb + arow + 12288 + so_);             \
    const bf16x8 bh0_ = *(const bf16x8*)(Bsb + brow +     0 + so_);             \
    const bf16x8 bh1_ = *(const bf16x8*)(Bsb + brow +  4096 + so_);             \
    MFMA_(bh0_, ah0_, acc00); MFMA_(bh0_, ah1_, acc01);                         \
    MFMA_(bh0_, ah2_, acc02); MFMA_(bh0_, ah3_, acc03);                         \
    MFMA_(bh1_, ah0_, acc10); MFMA_(bh1_, ah1_, acc11);                         \
    MFMA_(bh1_, ah2_, acc12); MFMA_(bh1_, ah3_, acc13);                         \
    const bf16x8 bl0_ = *(const bf16x8*)(Bsb + brow +     0 + (so_ ^ 128));     \
    const bf16x8 bl1_ = *(const bf16x8*)(Bsb + brow +  4096 + (so_ ^ 128));     \
    MFMA_(bl0_, ah0_, acc00); MFMA_(bl0_, ah1_, acc01);                         \
    MFMA_(bl0_, ah2_, acc02); MFMA_(bl0_, ah3_, acc03);                         \
    MFMA_(bl1_, ah0_, acc10); MFMA_(bl1_, ah1_, acc11);                         \
    MFMA_(bl1_, ah2_, acc12); MFMA_(bl1_, ah3_, acc13);                         \
    const bf16x8 al0_ = *(const bf16x8*)(Asb + arow +     0 + (so_ ^ 128));     \
    const bf16x8 al1_ = *(const bf16x8*)(Asb + arow +  4096 + (so_ ^ 128));     \
    const bf16x8 al2_ = *(const bf16x8*)(Asb + arow +  8192 + (so_ ^ 128));     \
    const bf16x8 al3_ = *(const bf16x8*)(Asb + arow + 12288 + (so_ ^ 128));     \
    MFMA_(bh0_, al0_, acc00); MFMA_(bh0_, al1_, acc01);                         \
    MFMA_(bh0_, al2_, acc02); MFMA_(bh0_, al3_, acc03);                         \
    MFMA_(bh1_, al0_, acc10); MFMA_(bh1_, al1_, acc11);                         \
    MFMA_(bh1_, al2_, acc12); MFMA_(bh1_, al3_, acc13);                         \
  }

#define EPI(I, J, ACC)                                                          \
  {                                                                             \
    const int hl_ = wn * 8 + (I) * 4 + lq;                                      \
    const int hg_ = hg0 + hl_;                                                  \
    const int ml_ = wm * 64 + (J) * 16 + l15;                                   \
    const int mg_ = mg0 + ml_;                                                  \
    const float4 b4_ = *(const float4*)(bias + 4 * hg_);                        \
    float g0_ = ACC[0] + b4_.x, g1_ = ACC[1] + b4_.y;                           \
    float g2_ = ACC[2] + b4_.z, g3_ = ACC[3] + b4_.w;                           \
    if (HASX) {                                                                 \
      const float x0_ = xptr[(size_t)mg_ * xstride + 0];                        \
      const float x1_ = xptr[(size_t)mg_ * xstride + 1];                        \
      const float4 wA_ = *(const float4*)(wih + 8 * hg_);                       \
      const float4 wB_ = *(const float4*)(wih + 8 * hg_ + 4);                   \
      g0_ += x0_ * wA_.x + x1_ * wA_.y;  g1_ += x0_ * wA_.z + x1_ * wA_.w;      \
      g2_ += x0_ * wB_.x + x1_ * wB_.y;  g3_ += x0_ * wB_.z + x1_ * wB_.w;      \
    }                                                                           \
    const float ig_ = sigm(g0_), fg_ = sigm(g1_);                               \
    const float gg_ = tanh_fast(g2_), og_ = sigm(g3_);                          \
    float* cp_ = CstT + (size_t)hg_ * BATCH + mg_;                              \
    const float cn_ = fg_ * (*cp_) + ig_ * gg_;                                 \
    *cp_ = cn_;                                                                 \
    const float hn_ = og_ * tanh_fast(cn_);                                     \
    const u16 hi_ = f2bf(hn_);                                                  \
    Hsh[ml_ * 17 + hl_] = hi_;                                                  \
    Hsl[ml_ * 17 + hl_] = f2bf(hn_ - bf2f(hi_));                                \
    if (PROJ) { s0##J += hn_ * wl[hg_]; s1##J += hn_ * wl[HID + hg_]; }         \
  }

// BM=128, BN=64, BK=64, pass-fused, global_load_lds staging (zero staging VGPR).
// LDS: As[128 rows][256B] + Bs[64][256B] = 49152 B, single-buffered, 3 WG/CU.
template <int KTOT, bool HASX, bool PROJ>
__device__ __forceinline__ void run_gemm(const GArgs& g, int mt, int nt, char* smem) {
  const u16* const Ax0 = g.Ax0;  const u16* const Ax1 = g.Ax1;
  const u16* const Bt  = g.Bt;
  const float* const bias = g.bias;
  const float* const xptr = g.xptr; const int xstride = g.xstride;
  const float* const wih  = g.wih;
  float* const CstT = g.CstT;
  u16* const Hx = g.Hx;
  const float* const wl = g.wl;
  float* const oacc = g.oacc;

  char* const Asb = smem;                    // 128 rows x 256B
  char* const Bsb = smem + 32768;            // 64 rows x 256B
  u16* const AsU = (u16*)Asb;
  u16* const BsU = (u16*)Bsb;

  const int tid = threadIdx.x;
  const int wid = tid >> 6, lane = tid & 63;
  const int wm = wid >> 1, wn = wid & 1;     // wm -> M half, wn -> N half
  const int l15 = lane & 15, lq = lane >> 4;
  const int sl0 = ((lq ^ l15) & 15) << 4;    // kk=0 hi-read slot byte
  const int arow = (wm * 64 + l15) * 256;
  const int brow = (wn * 32 + l15) * 256;

  const int lrow = lane >> 4;                // 0..3 (row within 4-row DMA group)
  const int lslot = lane & 15;               // 16B slot

  // per-lane source bases (u16 units)
  const u16* const aR = Ax0 + (size_t)(mt * 128) * 1024 + (size_t)lrow * 1024 + lslot * 8;
  const u16* const aR2 = (KTOT == 1024)
      ? (Ax1 + (size_t)(mt * 128) * 1024 + (size_t)lrow * 1024 + lslot * 8) : aR;
  constexpr int BRS = 2 * KTOT;              // B row stride (u16)
  const u16* const bR = Bt + (size_t)(nt * 64) * BRS + (size_t)lrow * BRS + lslot * 8;

  f32x4 acc00 = {}, acc01 = {}, acc02 = {}, acc03 = {};
  f32x4 acc10 = {}, acc11 = {}, acc12 = {}, acc13 = {};
  constexpr int TOT = KTOT / 64;

  for (int ks = 0; ks < TOT; ++ks) {
    __syncthreads();                         // prev compute done, LDS free
    // issue 12 global_load_lds per wave (A: 8, B: 4) -- no staging registers
    const u16* ap = (KTOT == 1024 && ks >= 8) ? aR2 : aR;
    const int ablk = (KTOT == 1024) ? (ks & 7) : ks;
    const size_t aoff = (size_t)ablk * 128;
#pragma unroll
    for (int i = 0; i < 8; ++i) {
      const int ii = wid * 8 + i;            // 0..31 -> rows 4ii..4ii+3
      glds16(ap + (size_t)(4 * ii) * 1024 + aoff, AsU + ii * 512);
    }
    const size_t boff = (size_t)ks * 128;
#pragma unroll
    for (int j = 0; j < 4; ++j) {
      const int jj = wid * 4 + j;            // 0..15 -> rows 4jj..4jj+3
      glds16(bR + (size_t)(4 * jj) * BRS + boff, BsU + jj * 512);
    }
    __syncthreads();                         // compiler drains vmcnt before barrier
    KKBODY(0);
    KKBODY(1);
  }

  // ---- in-register epilogue ----
  __syncthreads();                           // LDS reads done; reuse for H stage
  u16* const Hsh = (u16*)smem;               // [128][17]
  u16* const Hsl = Hsh + 128 * 17;

  const int mg0 = mt * 128, hg0 = nt * 16;
  float s00 = 0.f, s01 = 0.f, s02 = 0.f, s03 = 0.f;
  float s10 = 0.f, s11 = 0.f, s12 = 0.f, s13 = 0.f;

  EPI(0, 0, acc00); EPI(1, 0, acc10);
  EPI(0, 1, acc01); EPI(1, 1, acc11);
  EPI(0, 2, acc02); EPI(1, 2, acc12);
  EPI(0, 3, acc03); EPI(1, 3, acc13);

  if (PROJ) {                                // reduce over lq (this wave's 8 h)
    s00 += __shfl_xor(s00, 16); s00 += __shfl_xor(s00, 32);
    s01 += __shfl_xor(s01, 16); s01 += __shfl_xor(s01, 32);
    s02 += __shfl_xor(s02, 16); s02 += __shfl_xor(s02, 32);
    s03 += __shfl_xor(s03, 16); s03 += __shfl_xor(s03, 32);
    s10 += __shfl_xor(s10, 16); s10 += __shfl_xor(s10, 32);
    s11 += __shfl_xor(s11, 16); s11 += __shfl_xor(s11, 32);
    s12 += __shfl_xor(s12, 16); s12 += __shfl_xor(s12, 32);
    s13 += __shfl_xor(s13, 16); s13 += __shfl_xor(s13, 32);
    if (lq == 0) {
      float* o0 = oacc + (size_t)(mg0 + wm * 64 +  0 + l15) * OUTW;
      float* o1 = oacc + (size_t)(mg0 + wm * 64 + 16 + l15) * OUTW;
      float* o2 = oacc + (size_t)(mg0 + wm * 64 + 32 + l15) * OUTW;
      float* o3 = oacc + (size_t)(mg0 + wm * 64 + 48 + l15) * OUTW;
      unsafeAtomicAdd(o0 + 0, s00); unsafeAtomicAdd(o0 + 1, s10);
      unsafeAtomicAdd(o1 + 0, s01); unsafeAtomicAdd(o1 + 1, s11);
      unsafeAtomicAdd(o2 + 0, s02); unsafeAtomicAdd(o2 + 1, s12);
      unsafeAtomicAdd(o3 + 0, s03); unsafeAtomicAdd(o3 + 1, s13);
    }
  }

  __syncthreads();                           // H stage complete
  // H writeback into swizzled Hx layout (so next step's gload_lds is linear):
  // logical H[mg][hg]: blk=hg>>6, k'=hg&63, hi chunk=k'>>3 at slot chunk^(mg&15).
#pragma unroll
  for (int q = 0; q < 8; ++q) {
    const int m = (tid >> 4) + 16 * q;       // 0..127
    const int c = tid & 15;
    const int mg = mg0 + m;
    const int hg = hg0 + c;
    const int kq = hg & 63;
    const int ch = kq >> 3, co = kq & 7;
    const int sw = mg & 15;
    u16* rowp = Hx + (size_t)mg * 1024 + (hg >> 6) * 128;
    rowp[((ch ^ sw) << 3) + co]       = Hsh[m * 17 + c];
    rowp[(((ch | 8) ^ sw) << 3) + co] = Hsl[m * 17 + c];
  }
}

// XCD-pinned tile mapping: xcd = bid&7 always owns nt in [xcd*4, xcd*4+4)
template <int KTOT, bool HASX, bool PROJ>
__global__ __launch_bounds__(256, 3) void step_single(GArgs ga) {
  __shared__ __align__(16) char smem[49152];
  int bid = blockIdx.x;
  int xc = bid & 7, j = bid >> 3;            // j in [0,32)
  int nt = xc * 4 + (j & 3);
  int mt = j >> 2;                           // 0..7
  run_gemm<KTOT, HASX, PROJ>(ga, mt, nt, smem);
}

// grid 512: bid<256 -> L2(t) (+proj), else -> L1(t+1)  (independent GEMMs)
__global__ __launch_bounds__(256, 3) void step_fused(GArgs g2, GArgs g1) {
  __shared__ __align__(16) char smem[49152];
  int bid = blockIdx.x;
  int b = bid & 255;
  int xc = b & 7, j = b >> 3;                // j in [0,32)
  int nt = xc * 4 + (j & 3);
  int mt = j >> 2;
  if (bid < 256) run_gemm<1024, false, true>(g2, mt, nt, smem);
  else           run_gemm<512, true, false>(g1, mt, nt, smem);
}

// ---------- host ----------
extern "C" void kernel_launch(void* const* d_in, const int* in_sizes, int n_in,
                              void* d_out, int out_size, void* d_ws, size_t ws_size,
                              hipStream_t stream) {
  const float* x    = (const float*)d_in[0];
  const float* Wih1 = (const float*)d_in[1];
  const float* Whh1 = (const float*)d_in[2];
  const float* b1   = (const float*)d_in[3];
  const float* Wih2 = (const float*)d_in[4];
  const float* Whh2 = (const float*)d_in[5];
  const float* b2   = (const float*)d_in[6];
  const float* Wl   = (const float*)d_in[7];
  const float* bl   = (const float*)d_in[8];
  float* out = (float*)d_out;
  (void)in_sizes; (void)n_in; (void)out_size; (void)ws_size;

  char* p = (char*)d_ws;
  auto alloc = [&](size_t bytes) -> char* {
    char* r = p; p += (bytes + 255) & ~(size_t)255; return r;
  };
  u16* Bt1 = (u16*)alloc((size_t)2048 * 1024 * 2);   // 4 MB swizzled panel
  u16* Bt2 = (u16*)alloc((size_t)2048 * 2048 * 2);   // 8 MB swizzled panel
  char* state0 = p;
  u16* Hxb[4];                                       // H1x[2], H2x[2] (ping-pong)
  for (int i = 0; i < 4; ++i) Hxb[i] = (u16*)alloc((size_t)BATCH * 1024 * 2);
  float* C1 = (float*)alloc((size_t)BATCH * HID * 4);  // stored [512][1024]
  float* C2 = (float*)alloc((size_t)BATCH * HID * 4);
  size_t state_bytes = (size_t)(p - state0);
  float* b1p = (float*)alloc(2048 * 4);
  float* b2p = (float*)alloc(2048 * 4);
  float* w1p = (float*)alloc(2048 * 2 * 4);

  hipMemsetAsync(state0, 0, state_bytes, stream);    // h,c = 0 (zeros swizzle to zeros)
  init_out<<<(BATCH * OUTW + 255) / 256, 256, 0, stream>>>(bl, out);
  prep_btx1<<<8192, 256, 0, stream>>>(Whh1, Bt1);
  prep_btx2<<<16384, 256, 0, stream>>>(Wih2, Whh2, Bt2);
  prep_small<<<8, 256, 0, stream>>>(b1, b2, Wih1, b1p, b2p, w1p);

  auto mkL1 = [&](int t) -> GArgs {
    int par = t & 1, prev = par ^ 1;
    GArgs a{};
    a.Ax0 = Hxb[0 + prev]; a.Ax1 = nullptr;
    a.Bt = Bt1; a.bias = b1p;
    a.xptr = (t < T_OBS) ? (x + 2 * t) : (out + 2 * (t - 1));
    a.xstride = (t < T_OBS) ? (2 * T_OBS) : OUTW;
    a.wih = w1p; a.CstT = C1;
    a.Hx = Hxb[0 + par];
    a.wl = nullptr; a.oacc = nullptr;
    return a;
  };
  auto mkL2 = [&](int t) -> GArgs {
    int par = t & 1, prev = par ^ 1;
    GArgs a{};
    a.Ax0 = Hxb[0 + par];   // k<512: H1(t)
    a.Ax1 = Hxb[2 + prev];  // k>=512: H2(t-1)
    a.Bt = Bt2; a.bias = b2p;
    a.xptr = nullptr; a.xstride = 0; a.wih = nullptr;
    a.CstT = C2;
    a.Hx = Hxb[2 + par];
    a.wl = Wl; a.oacc = out + 2 * t;
    return a;
  };

  // step 0 layer 1
  step_single<512, true, false><<<256, 256, 0, stream>>>(mkL1(0));
  // observed steps: L2(t) and L1(t+1) are independent -> one 512-WG dispatch
  for (int t = 0; t < T_OBS - 1; ++t)
    step_fused<<<512, 256, 0, stream>>>(mkL2(t), mkL1(t + 1));
  // last observed L2 (writes out[63])
  step_single<1024, false, true><<<256, 256, 0, stream>>>(mkL2(T_OBS - 1));
  // future steps: strict chain L1 -> L2(+proj) -> L1 ...
  for (int t = T_OBS; t < NSTEPS; ++t) {
    step_single<512, true, false><<<256, 256, 0, stream>>>(mkL1(t));
    step_single<1024, false, true><<<256, 256, 0, stream>>>(mkL2(t));
  }
}